// Round 9
// baseline (182.401 us; speedup 1.0000x reference)
//
#include <hip/hip_runtime.h>
#include <hip/hip_fp16.h>

#define NF    512
#define BLKE  4096
#define SHIFT 7
#define NPB   128      // nodes per bucket

__device__ inline float4 f4fma(float4 a, float s, float4 b){
  return make_float4(fmaf(s,b.x,a.x), fmaf(s,b.y,a.y), fmaf(s,b.z,a.z), fmaf(s,b.w,a.w));
}

union PK4 { uint4 u; __half2 h[4]; };
union PK2 { uint2 u; __half2 h[2]; };

// ---- Pass A: per-block bucket grouping (4096 edges/block), detect int64 inline ----
__global__ __launch_bounds__(256) void k_blocal(const int* __restrict__ ei, int E, int nbuck,
                                                int* __restrict__ ebuf, int* __restrict__ cnt2d,
                                                int* __restrict__ lpos2d){
  __shared__ int lh[2048];
  __shared__ int part[256];
  __shared__ int lbuf[BLKE];
  __shared__ int s_is64;
  int t = threadIdx.x;
  int blk = blockIdx.x;
  int e0 = blk * BLKE;
  int cnt = min(BLKE, E - e0);

  if (t == 0) s_is64 = 1;
  __syncthreads();
  int found = 0;
  for (int k = t; k < min(cnt, 2048); k += 256) found |= (ei[2*(e0+k)+1] != 0);
  if (found) s_is64 = 0;
  __syncthreads();
  int is64 = s_is64;

  int rr[16], cc[16];
  #pragma unroll
  for (int j = 0; j < 16; ++j){
    int k = j*256 + t;
    int idx = e0 + k;
    if (k < cnt){
      if (is64){ rr[j] = ei[2*idx]; cc[j] = ei[2*(E+idx)]; }
      else     { rr[j] = ei[idx];   cc[j] = ei[E+idx];     }
    } else { rr[j] = -1; cc[j] = 0; }
  }

  for (int i = t; i < nbuck; i += 256) lh[i] = 0;
  __syncthreads();
  #pragma unroll
  for (int j = 0; j < 16; ++j)
    if (rr[j] >= 0) atomicAdd(&lh[cc[j] >> SHIFT], 1);
  __syncthreads();

  int per = (nbuck + 255) >> 8;   // <= 8
  int myv[8];
  int s = 0;
  #pragma unroll
  for (int j = 0; j < 8; ++j){
    int i = t*per + j;
    int v = (j < per && i < nbuck) ? lh[i] : 0;
    myv[j] = v; s += v;
  }
  part[t] = s; __syncthreads();
  for (int off = 1; off < 256; off <<= 1){
    int a = part[t];
    int u = (t >= off) ? part[t-off] : 0;
    __syncthreads();
    part[t] = a + u;
    __syncthreads();
  }
  int run = part[t] - s;
  #pragma unroll
  for (int j = 0; j < 8; ++j){
    int i = t*per + j;
    if (j < per && i < nbuck){
      cnt2d [(size_t)blk*nbuck + i] = myv[j];
      lpos2d[(size_t)blk*nbuck + i] = run;
      lh[i] = run;
      run += myv[j];
    }
  }
  __syncthreads();

  #pragma unroll
  for (int j = 0; j < 16; ++j){
    if (rr[j] >= 0){
      int b = cc[j] >> SHIFT;
      int p = atomicAdd(&lh[b], 1);
      lbuf[p] = (rr[j] << SHIFT) | (cc[j] & (NPB-1));
    }
  }
  __syncthreads();
  for (int k = t; k < cnt; k += 256) ebuf[e0 + k] = lbuf[k];   // coalesced flush
}

// ---- Pass B: per-bucket segment tables (bucket-major) + btot. NO ebuf read. ----
__global__ __launch_bounds__(256) void k_meta(const int* __restrict__ cnt2d, const int* __restrict__ lpos2d,
                                              int nblk, int nbuck,
                                              int* __restrict__ soffT, int* __restrict__ sbaseT,
                                              int* __restrict__ btot){
  __shared__ int soff[1025];
  __shared__ int sbase[1024];
  __shared__ int part[256];
  int b = blockIdx.x, t = threadIdx.x;

  int per = (nblk + 255) >> 8;   // <= 4 (nblk <= 1024)
  int myv[4];
  int s = 0;
  #pragma unroll
  for (int j = 0; j < 4; ++j){
    int i = t*per + j;
    int v = 0;
    if (j < per && i < nblk){
      v = cnt2d[(size_t)i*nbuck + b];
      sbase[i] = i*BLKE + lpos2d[(size_t)i*nbuck + b];
    }
    myv[j] = v; s += v;
  }
  part[t] = s; __syncthreads();
  for (int off = 1; off < 256; off <<= 1){
    int a = part[t];
    int u = (t >= off) ? part[t-off] : 0;
    __syncthreads();
    part[t] = a + u;
    __syncthreads();
  }
  int run = part[t] - s;
  #pragma unroll
  for (int j = 0; j < 4; ++j){
    int i = t*per + j;
    if (j < per && i < nblk){
      soff[i] = run;
      run += myv[j];
    }
  }
  if (t == 255){ soff[nblk] = part[255]; btot[b] = part[255]; }
  __syncthreads();

  for (int i = t; i <= nblk; i += 256) soffT[(size_t)b*(nblk+1) + i] = soff[i];
  for (int i = t; i < nblk;  i += 256) sbaseT[(size_t)b*nblk + i]   = sbase[i];
}

// ---- Pass C: per-bucket stage->count->scan->scatter; emits degi/dis/offs/csr; inline ebase ----
__global__ __launch_bounds__(256) void k_bsort(const int* __restrict__ ebuf, const int* __restrict__ soffT,
                                               const int* __restrict__ sbaseT, const int* __restrict__ btot,
                                               int* __restrict__ degi, float* __restrict__ dis,
                                               int* __restrict__ offs, int* __restrict__ csr,
                                               int N, int nblk){
  __shared__ int soff[1025];
  __shared__ int sbase[1024];
  __shared__ int partE[256];
  __shared__ int lcnt[NPB];
  __shared__ int sd[NPB];
  __shared__ int lbuf[8192];
  int b = blockIdx.x, t = threadIdx.x;
  int n0 = b * NPB;
  int nn = min(NPB, N - n0);

  // ebase[b] = sum btot[0..b)
  int accE = 0;
  for (int i = t; i < b; i += 256) accE += btot[i];
  partE[t] = accE; __syncthreads();
  for (int off = 128; off > 0; off >>= 1){
    if (t < off) partE[t] += partE[t + off];
    __syncthreads();
  }
  int eb = partE[0];

  for (int i = t; i <= nblk; i += 256) soff[i] = soffT[(size_t)b*(nblk+1) + i];
  for (int i = t; i < nblk;  i += 256) sbase[i] = sbaseT[(size_t)b*nblk + i];
  if (t < NPB) lcnt[t] = 0;
  __syncthreads();

  int size = soff[nblk];
  bool staged = (size <= 8192);

  // pass 1: merge-path march — stage into LDS + count per node
  int PER = (size + 255) >> 8;
  int k = t * PER, kend = min(k + PER, size);
  if (k < kend){
    int lo = 0, hi = nblk - 1;
    while (lo < hi){ int mid = (lo + hi + 1) >> 1; if (soff[mid] <= k) lo = mid; else hi = mid - 1; }
    int seg = lo;
    while (k < kend){
      int se = soff[seg+1];
      const int* src = ebuf + sbase[seg] - soff[seg];
      int e1 = min(kend, se);
      for (; k < e1; ++k){
        int v = src[k];
        if (staged) lbuf[k] = v;
        atomicAdd(&lcnt[v & (NPB-1)], 1);
      }
      ++seg;
    }
  }
  __syncthreads();

  // emit degi/dis; scan counts -> cursors + offs
  int own = 0;
  if (t < nn){
    own = lcnt[t];
    degi[n0 + t] = own;
    dis[n0 + t]  = rsqrtf((float)(own + 1));   // +1 self-loop
    sd[t] = own;
  }
  __syncthreads();
  for (int off = 1; off < NPB; off <<= 1){
    int v = (t < nn && t >= off) ? sd[t-off] : 0;
    __syncthreads();
    if (t < nn) sd[t] += v;
    __syncthreads();
  }
  if (t < nn){
    int pref = sd[t] - own;
    lcnt[t] = pref;
    offs[n0 + t] = eb + pref;
  }
  __syncthreads();

  // pass 2: scatter
  if (staged){
    for (int k2 = t; k2 < size; k2 += 256){
      int v = lbuf[k2];
      int p = atomicAdd(&lcnt[v & (NPB-1)], 1);
      csr[eb + p] = v >> SHIFT;
    }
  } else {
    int k3 = t * PER, kend3 = min(k3 + PER, size);
    if (k3 < kend3){
      int lo = 0, hi = nblk - 1;
      while (lo < hi){ int mid = (lo + hi + 1) >> 1; if (soff[mid] <= k3) lo = mid; else hi = mid - 1; }
      int seg = lo;
      while (k3 < kend3){
        int se = soff[seg+1];
        const int* src = ebuf + sbase[seg] - soff[seg];
        int e1 = min(kend3, se);
        for (; k3 < e1; ++k3){
          int v = src[k3];
          int p = atomicAdd(&lcnt[v & (NPB-1)], 1);
          csr[eb + p] = v >> SHIFT;
        }
        ++seg;
      }
    }
  }
}

// ---- hs1 = fp16( dis * (x @ W1) ); BM=128, BK=32, DOUBLE-BUFFERED LDS ----
__global__ __launch_bounds__(256) void k_gemm1(const float* __restrict__ x, const float* __restrict__ W1,
                                               const float* __restrict__ dis, __half* __restrict__ hs1h, int N){
  __shared__ float xs[2][128*36];
  __shared__ float wc[2][512];
  int t  = threadIdx.x;
  int R0 = blockIdx.x*128;
  int lr = t >> 3;
  int lc = (t & 7) * 4;
  int rt = t >> 2;
  int jq = t & 3;

  // clamped source rows for the 4 load slots
  int grc[4];
  #pragma unroll
  for (int li = 0; li < 4; ++li){
    int gr = R0 + lr + li*32;
    grc[li] = (gr < N) ? gr : 0;
  }

  float4 vx[4];
  float vw0, vw1;
  // prologue: load chunk 0
  #pragma unroll
  for (int li = 0; li < 4; ++li)
    vx[li] = *(const float4*)(x + (size_t)grc[li]*NF + 0 + lc);
  vw0 = W1[t]; vw1 = W1[t + 256];
  #pragma unroll
  for (int li = 0; li < 4; ++li)
    *(float4*)(xs[0] + (lr + li*32)*36 + lc) = vx[li];
  wc[0][t] = vw0; wc[0][t + 256] = vw1;
  __syncthreads();

  float4 acc0 = make_float4(0,0,0,0), acc1 = acc0;

  for (int kc = 0; kc < 16; ++kc){
    int cb = kc & 1;
    if (kc < 15){
      int koff = (kc + 1) * 32;
      #pragma unroll
      for (int li = 0; li < 4; ++li)
        vx[li] = *(const float4*)(x + (size_t)grc[li]*NF + koff + lc);
      vw0 = W1[koff*16 + t]; vw1 = W1[koff*16 + t + 256];
    }

    const float* xb = xs[cb];
    const float* wb = wc[cb];
    #pragma unroll
    for (int k0 = 0; k0 < 32; k0 += 4){
      float4 xr0 = *(const float4*)(xb + (rt*2+0)*36 + k0);
      float4 xr1 = *(const float4*)(xb + (rt*2+1)*36 + k0);
      float4 w0  = *(const float4*)(wb + (k0+0)*16 + jq*4);
      float4 w1  = *(const float4*)(wb + (k0+1)*16 + jq*4);
      float4 w2  = *(const float4*)(wb + (k0+2)*16 + jq*4);
      float4 w3  = *(const float4*)(wb + (k0+3)*16 + jq*4);
      acc0 = f4fma(acc0, xr0.x, w0); acc0 = f4fma(acc0, xr0.y, w1); acc0 = f4fma(acc0, xr0.z, w2); acc0 = f4fma(acc0, xr0.w, w3);
      acc1 = f4fma(acc1, xr1.x, w0); acc1 = f4fma(acc1, xr1.y, w1); acc1 = f4fma(acc1, xr1.z, w2); acc1 = f4fma(acc1, xr1.w, w3);
    }

    if (kc < 15){
      int nb = cb ^ 1;
      #pragma unroll
      for (int li = 0; li < 4; ++li)
        *(float4*)(xs[nb] + (lr + li*32)*36 + lc) = vx[li];
      wc[nb][t] = vw0; wc[nb][t + 256] = vw1;
      __syncthreads();
    }
  }

  #pragma unroll
  for (int m = 0; m < 2; ++m){
    int gr = R0 + rt*2 + m;
    if (gr < N){
      float d = dis[gr];
      float4 a = (m==0) ? acc0 : acc1;
      PK2 pk;
      pk.h[0] = __float22half2_rn(make_float2(a.x*d, a.y*d));
      pk.h[1] = __float22half2_rn(make_float2(a.z*d, a.w*d));
      *(uint2*)(hs1h + (size_t)gr*16 + jq*4) = pk.u;
    }
  }
}

// ---- layer1 aggregate + bias/ReLU + xW2 -> hs2 fp16; 4 threads/node, chunked 2-phase ----
__global__ __launch_bounds__(256) void k_agg1(const __half* __restrict__ hs1h, const int* __restrict__ offs,
                                              const int* __restrict__ degi, const int* __restrict__ csr,
                                              const float* __restrict__ dis, const float* __restrict__ b1,
                                              const float* __restrict__ W2, __half* __restrict__ hs2h, int N){
  __shared__ float sW[112];
  __shared__ float sb[16];
  int t = threadIdx.x;
  if (t < 112) sW[t] = W2[t];
  if (t < 16)  sb[t] = b1[t];
  __syncthreads();

  int g = blockIdx.x*256 + t;
  int n = g >> 2;
  int q = g & 1;         // feature half
  int h = (g >> 1) & 1;  // edge parity
  if (n >= N) return;

  float a0[8] = {0,0,0,0,0,0,0,0};
  int st = offs[n], cnt = degi[n];

  for (int base = h; base < cnt; base += 16){
    int rr[8], ii[8];
    #pragma unroll
    for (int j = 0; j < 8; ++j){
      int i2 = base + 2*j;
      ii[j] = i2;
      int ic = (i2 < cnt) ? i2 : 0;
      rr[j] = csr[st + ic];
    }
    PK4 p[8];
    #pragma unroll
    for (int j = 0; j < 8; ++j)
      p[j].u = *(const uint4*)(hs1h + (size_t)rr[j]*16 + q*8);
    #pragma unroll
    for (int j = 0; j < 8; ++j){
      if (ii[j] < cnt){
        #pragma unroll
        for (int jj = 0; jj < 4; ++jj){
          float2 f = __half22float2(p[j].h[jj]);
          a0[2*jj]   += f.x;
          a0[2*jj+1] += f.y;
        }
      }
    }
  }
  // combine edge halves (lanes differing in bit 1)
  #pragma unroll
  for (int j = 0; j < 8; ++j) a0[j] += __shfl_xor(a0[j], 2);

  // self-loop term
  {
    PK4 ps; ps.u = *(const uint4*)(hs1h + (size_t)n*16 + q*8);
    #pragma unroll
    for (int jj = 0; jj < 4; ++jj){
      float2 fs = __half22float2(ps.h[jj]);
      a0[2*jj] += fs.x; a0[2*jj+1] += fs.y;
    }
  }

  float d = dis[n];
  float e[8];
  #pragma unroll
  for (int j = 0; j < 8; ++j)
    e[j] = fmaxf(fmaf(d, a0[j], sb[q*8 + j]), 0.f);

  float o[7] = {0,0,0,0,0,0,0};
  #pragma unroll
  for (int j = 0; j < 8; ++j){
    int f = q*8 + j;
    #pragma unroll
    for (int c = 0; c < 7; ++c) o[c] = fmaf(e[j], sW[f*7 + c], o[c]);
  }
  // combine feature halves (lanes differing in bit 0)
  #pragma unroll
  for (int c = 0; c < 7; ++c) o[c] += __shfl_xor(o[c], 1);

  if (q == 0 && h == 0){
    PK4 pk;
    pk.h[0] = __float22half2_rn(make_float2(o[0]*d, o[1]*d));
    pk.h[1] = __float22half2_rn(make_float2(o[2]*d, o[3]*d));
    pk.h[2] = __float22half2_rn(make_float2(o[4]*d, o[5]*d));
    pk.h[3] = __float22half2_rn(make_float2(o[6]*d, 0.f));
    *(uint4*)(hs2h + (size_t)n*8) = pk.u;
  }
}

// ---- layer2 aggregate + bias -> out fp32; 2 threads/node, chunked 2-phase ----
__global__ __launch_bounds__(256) void k_agg2(const __half* __restrict__ hs2h, const int* __restrict__ offs,
                                              const int* __restrict__ degi, const int* __restrict__ csr,
                                              const float* __restrict__ dis, const float* __restrict__ b2,
                                              float* __restrict__ out, int N){
  int g = blockIdx.x*256 + threadIdx.x;
  int n = g >> 1, h = g & 1;
  if (n >= N) return;

  float a0[7] = {0,0,0,0,0,0,0};
  int st = offs[n], cnt = degi[n];

  for (int base = h; base < cnt; base += 16){
    int rr[8], ii[8];
    #pragma unroll
    for (int j = 0; j < 8; ++j){
      int i2 = base + 2*j;
      ii[j] = i2;
      int ic = (i2 < cnt) ? i2 : 0;
      rr[j] = csr[st + ic];
    }
    PK4 p[8];
    #pragma unroll
    for (int j = 0; j < 8; ++j)
      p[j].u = *(const uint4*)(hs2h + (size_t)rr[j]*8);
    #pragma unroll
    for (int j = 0; j < 8; ++j){
      if (ii[j] < cnt){
        float2 f0 = __half22float2(p[j].h[0]);
        float2 f1 = __half22float2(p[j].h[1]);
        float2 f2 = __half22float2(p[j].h[2]);
        float2 f3 = __half22float2(p[j].h[3]);
        a0[0] += f0.x; a0[1] += f0.y;
        a0[2] += f1.x; a0[3] += f1.y;
        a0[4] += f2.x; a0[5] += f2.y;
        a0[6] += f3.x;
      }
    }
  }
  #pragma unroll
  for (int c = 0; c < 7; ++c) a0[c] += __shfl_xor(a0[c], 1);

  if (h == 0){
    float d = dis[n];
    PK4 ps; ps.u = *(const uint4*)(hs2h + (size_t)n*8);
    float s0 = __half22float2(ps.h[0]).x, s1 = __half22float2(ps.h[0]).y;
    float s2 = __half22float2(ps.h[1]).x, s3 = __half22float2(ps.h[1]).y;
    float s4 = __half22float2(ps.h[2]).x, s5 = __half22float2(ps.h[2]).y;
    float s6 = __half22float2(ps.h[3]).x;
    float* o = out + (size_t)n*7;
    o[0] = fmaf(d, a0[0] + s0, b2[0]);
    o[1] = fmaf(d, a0[1] + s1, b2[1]);
    o[2] = fmaf(d, a0[2] + s2, b2[2]);
    o[3] = fmaf(d, a0[3] + s3, b2[3]);
    o[4] = fmaf(d, a0[4] + s4, b2[4]);
    o[5] = fmaf(d, a0[5] + s5, b2[5]);
    o[6] = fmaf(d, a0[6] + s6, b2[6]);
  }
}

extern "C" void kernel_launch(void* const* d_in, const int* in_sizes, int n_in,
                              void* d_out, int out_size, void* d_ws, size_t ws_size,
                              hipStream_t stream){
  const float* x  = (const float*)d_in[0];
  const int*   ei = (const int*)d_in[1];
  const float* W1 = (const float*)d_in[2];
  const float* b1 = (const float*)d_in[3];
  const float* W2 = (const float*)d_in[4];
  const float* b2 = (const float*)d_in[5];
  float* out = (float*)d_out;

  const int N = in_sizes[0] / NF;      // 100000
  const int E = in_sizes[1] / 2;       // 3200000

  const int nbuck = (N + NPB - 1) / NPB;    // 782 (<= 2048)
  const int nblk  = (E + BLKE - 1) / BLKE;  // 782 (<= 1024 for E <= 4.19M)

  char* w = (char*)d_ws;
  size_t cur = 0;
  auto alloc = [&](size_t bytes)->char*{ char* p = w + cur; cur += (bytes + 255) & ~(size_t)255; return p; };
  int*    cnt2d  = (int*)   alloc((size_t)nblk*nbuck*4);
  int*    lpos2d = (int*)   alloc((size_t)nblk*nbuck*4);
  int*    soffT  = (int*)   alloc((size_t)nbuck*(nblk+1)*4);
  int*    sbaseT = (int*)   alloc((size_t)nbuck*nblk*4);
  int*    btot   = (int*)   alloc((size_t)(nbuck+1)*4);
  int*    degi   = (int*)   alloc((size_t)N*4);
  float*  dis    = (float*) alloc((size_t)N*4);
  int*    offs   = (int*)   alloc((size_t)N*4);
  int*    ebuf   = (int*)   alloc((size_t)nblk*BLKE*4);
  int*    csr    = (int*)   alloc((size_t)E*4);
  __half* hs1h   = (__half*)alloc((size_t)N*16*2);
  __half* hs2h   = (__half*)alloc((size_t)N*8*2);
  (void)ws_size; (void)n_in; (void)out_size;

  int gM  = (N + 127) / 128;
  int g2N = (2*N + 255) / 256;
  int g4N = (4*N + 255) / 256;

  k_blocal<<<nblk, 256, 0, stream>>>(ei, E, nbuck, ebuf, cnt2d, lpos2d);
  k_meta  <<<nbuck, 256, 0, stream>>>(cnt2d, lpos2d, nblk, nbuck, soffT, sbaseT, btot);
  k_bsort <<<nbuck, 256, 0, stream>>>(ebuf, soffT, sbaseT, btot, degi, dis, offs, csr, N, nblk);
  k_gemm1 <<<gM, 256, 0, stream>>>(x, W1, dis, hs1h, N);
  k_agg1  <<<g4N, 256, 0, stream>>>(hs1h, offs, degi, csr, dis, b1, W2, hs2h, N);
  k_agg2  <<<g2N, 256, 0, stream>>>(hs2h, offs, degi, csr, dis, b2, out, N);
}

// Round 10
// 165.900 us; speedup vs baseline: 1.0995x; 1.0995x over previous
//
#include <hip/hip_runtime.h>
#include <hip/hip_fp16.h>

#define NF    512
#define BLKE  4096
#define SHIFT 7
#define NPB   128      // nodes per bucket

__device__ inline float4 f4fma(float4 a, float s, float4 b){
  return make_float4(fmaf(s,b.x,a.x), fmaf(s,b.y,a.y), fmaf(s,b.z,a.z), fmaf(s,b.w,a.w));
}

union PK4 { uint4 u; __half2 h[4]; };
union PK2 { uint2 u; __half2 h[2]; };

// ---- Pass A: per-block bucket grouping (4096 edges/block), detect int64 inline ----
__global__ __launch_bounds__(256) void k_blocal(const int* __restrict__ ei, int E, int nbuck,
                                                int* __restrict__ ebuf, int* __restrict__ cnt2d,
                                                int* __restrict__ lpos2d){
  __shared__ int lh[2048];
  __shared__ int part[256];
  __shared__ int lbuf[BLKE];
  __shared__ int s_is64;
  int t = threadIdx.x;
  int blk = blockIdx.x;
  int e0 = blk * BLKE;
  int cnt = min(BLKE, E - e0);

  if (t == 0) s_is64 = 1;
  __syncthreads();
  int found = 0;
  for (int k = t; k < min(cnt, 2048); k += 256) found |= (ei[2*(e0+k)+1] != 0);
  if (found) s_is64 = 0;
  __syncthreads();
  int is64 = s_is64;

  int rr[16], cc[16];
  #pragma unroll
  for (int j = 0; j < 16; ++j){
    int k = j*256 + t;
    int idx = e0 + k;
    if (k < cnt){
      if (is64){ rr[j] = ei[2*idx]; cc[j] = ei[2*(E+idx)]; }
      else     { rr[j] = ei[idx];   cc[j] = ei[E+idx];     }
    } else { rr[j] = -1; cc[j] = 0; }
  }

  for (int i = t; i < nbuck; i += 256) lh[i] = 0;
  __syncthreads();
  #pragma unroll
  for (int j = 0; j < 16; ++j)
    if (rr[j] >= 0) atomicAdd(&lh[cc[j] >> SHIFT], 1);
  __syncthreads();

  int per = (nbuck + 255) >> 8;   // <= 8
  int myv[8];
  int s = 0;
  #pragma unroll
  for (int j = 0; j < 8; ++j){
    int i = t*per + j;
    int v = (j < per && i < nbuck) ? lh[i] : 0;
    myv[j] = v; s += v;
  }
  part[t] = s; __syncthreads();
  for (int off = 1; off < 256; off <<= 1){
    int a = part[t];
    int u = (t >= off) ? part[t-off] : 0;
    __syncthreads();
    part[t] = a + u;
    __syncthreads();
  }
  int run = part[t] - s;
  #pragma unroll
  for (int j = 0; j < 8; ++j){
    int i = t*per + j;
    if (j < per && i < nbuck){
      cnt2d [(size_t)blk*nbuck + i] = myv[j];
      lpos2d[(size_t)blk*nbuck + i] = run;
      lh[i] = run;
      run += myv[j];
    }
  }
  __syncthreads();

  #pragma unroll
  for (int j = 0; j < 16; ++j){
    if (rr[j] >= 0){
      int b = cc[j] >> SHIFT;
      int p = atomicAdd(&lh[b], 1);
      lbuf[p] = (rr[j] << SHIFT) | (cc[j] & (NPB-1));
    }
  }
  __syncthreads();
  for (int k = t; k < cnt; k += 256) ebuf[e0 + k] = lbuf[k];   // coalesced flush
}

// ---- Pass B: per-bucket segment tables (bucket-major) + btot. NO ebuf read. ----
__global__ __launch_bounds__(256) void k_meta(const int* __restrict__ cnt2d, const int* __restrict__ lpos2d,
                                              int nblk, int nbuck,
                                              int* __restrict__ soffT, int* __restrict__ sbaseT,
                                              int* __restrict__ btot){
  __shared__ int soff[1025];
  __shared__ int sbase[1024];
  __shared__ int part[256];
  int b = blockIdx.x, t = threadIdx.x;

  int per = (nblk + 255) >> 8;   // <= 4 (nblk <= 1024)
  int myv[4];
  int s = 0;
  #pragma unroll
  for (int j = 0; j < 4; ++j){
    int i = t*per + j;
    int v = 0;
    if (j < per && i < nblk){
      v = cnt2d[(size_t)i*nbuck + b];
      sbase[i] = i*BLKE + lpos2d[(size_t)i*nbuck + b];
    }
    myv[j] = v; s += v;
  }
  part[t] = s; __syncthreads();
  for (int off = 1; off < 256; off <<= 1){
    int a = part[t];
    int u = (t >= off) ? part[t-off] : 0;
    __syncthreads();
    part[t] = a + u;
    __syncthreads();
  }
  int run = part[t] - s;
  #pragma unroll
  for (int j = 0; j < 4; ++j){
    int i = t*per + j;
    if (j < per && i < nblk){
      soff[i] = run;
      run += myv[j];
    }
  }
  if (t == 255){ soff[nblk] = part[255]; btot[b] = part[255]; }
  __syncthreads();

  for (int i = t; i <= nblk; i += 256) soffT[(size_t)b*(nblk+1) + i] = soff[i];
  for (int i = t; i < nblk;  i += 256) sbaseT[(size_t)b*nblk + i]   = sbase[i];
}

// ---- Pass C: per-bucket stage->count->scan->scatter; emits degi/dis/offs/csr; inline ebase ----
__global__ __launch_bounds__(256) void k_bsort(const int* __restrict__ ebuf, const int* __restrict__ soffT,
                                               const int* __restrict__ sbaseT, const int* __restrict__ btot,
                                               int* __restrict__ degi, float* __restrict__ dis,
                                               int* __restrict__ offs, int* __restrict__ csr,
                                               int N, int nblk){
  __shared__ int soff[1025];
  __shared__ int sbase[1024];
  __shared__ int partE[256];
  __shared__ int lcnt[NPB];
  __shared__ int sd[NPB];
  __shared__ int lbuf[6144];   // mean bucket = 4092, sigma ~64; fallback path covers overflow
  int b = blockIdx.x, t = threadIdx.x;
  int n0 = b * NPB;
  int nn = min(NPB, N - n0);

  // ebase[b] = sum btot[0..b)
  int accE = 0;
  for (int i = t; i < b; i += 256) accE += btot[i];
  partE[t] = accE; __syncthreads();
  for (int off = 128; off > 0; off >>= 1){
    if (t < off) partE[t] += partE[t + off];
    __syncthreads();
  }
  int eb = partE[0];

  for (int i = t; i <= nblk; i += 256) soff[i] = soffT[(size_t)b*(nblk+1) + i];
  for (int i = t; i < nblk;  i += 256) sbase[i] = sbaseT[(size_t)b*nblk + i];
  if (t < NPB) lcnt[t] = 0;
  __syncthreads();

  int size = soff[nblk];
  bool staged = (size <= 6144);

  // pass 1: merge-path march — stage into LDS + count per node
  int PER = (size + 255) >> 8;
  int k = t * PER, kend = min(k + PER, size);
  if (k < kend){
    int lo = 0, hi = nblk - 1;
    while (lo < hi){ int mid = (lo + hi + 1) >> 1; if (soff[mid] <= k) lo = mid; else hi = mid - 1; }
    int seg = lo;
    while (k < kend){
      int se = soff[seg+1];
      const int* src = ebuf + sbase[seg] - soff[seg];
      int e1 = min(kend, se);
      for (; k < e1; ++k){
        int v = src[k];
        if (staged) lbuf[k] = v;
        atomicAdd(&lcnt[v & (NPB-1)], 1);
      }
      ++seg;
    }
  }
  __syncthreads();

  // emit degi/dis; scan counts -> cursors + offs
  int own = 0;
  if (t < nn){
    own = lcnt[t];
    degi[n0 + t] = own;
    dis[n0 + t]  = rsqrtf((float)(own + 1));   // +1 self-loop
    sd[t] = own;
  }
  __syncthreads();
  for (int off = 1; off < NPB; off <<= 1){
    int v = (t < nn && t >= off) ? sd[t-off] : 0;
    __syncthreads();
    if (t < nn) sd[t] += v;
    __syncthreads();
  }
  if (t < nn){
    int pref = sd[t] - own;
    lcnt[t] = pref;
    offs[n0 + t] = eb + pref;
  }
  __syncthreads();

  // pass 2: scatter
  if (staged){
    for (int k2 = t; k2 < size; k2 += 256){
      int v = lbuf[k2];
      int p = atomicAdd(&lcnt[v & (NPB-1)], 1);
      csr[eb + p] = v >> SHIFT;
    }
  } else {
    int k3 = t * PER, kend3 = min(k3 + PER, size);
    if (k3 < kend3){
      int lo = 0, hi = nblk - 1;
      while (lo < hi){ int mid = (lo + hi + 1) >> 1; if (soff[mid] <= k3) lo = mid; else hi = mid - 1; }
      int seg = lo;
      while (k3 < kend3){
        int se = soff[seg+1];
        const int* src = ebuf + sbase[seg] - soff[seg];
        int e1 = min(kend3, se);
        for (; k3 < e1; ++k3){
          int v = src[k3];
          int p = atomicAdd(&lcnt[v & (NPB-1)], 1);
          csr[eb + p] = v >> SHIFT;
        }
        ++seg;
      }
    }
  }
}

// ---- hs1 = fp16( dis * (x @ W1) ); BM=128, BK=32, single-buffer (R8-proven) ----
__global__ __launch_bounds__(256) void k_gemm1(const float* __restrict__ x, const float* __restrict__ W1,
                                               const float* __restrict__ dis, __half* __restrict__ hs1h, int N){
  __shared__ float xs[128*36];
  __shared__ float wc[32*16];
  int t  = threadIdx.x;
  int R0 = blockIdx.x*128;
  int lr = t >> 3;
  int lc = (t & 7) * 4;
  int rt = t >> 2;
  int jq = t & 3;

  float4 acc0 = make_float4(0,0,0,0), acc1 = acc0;

  for (int kc = 0; kc < NF; kc += 32){
    #pragma unroll
    for (int li = 0; li < 4; ++li){
      int row = lr + li*32;
      int gr  = R0 + row;
      int grc = (gr < N) ? gr : 0;
      float4 v = *(const float4*)(x + (size_t)grc*NF + kc + lc);
      *(float4*)(xs + row*36 + lc) = v;
    }
    wc[t]       = W1[kc*16 + t];
    wc[t + 256] = W1[kc*16 + t + 256];
    __syncthreads();

    #pragma unroll
    for (int k0 = 0; k0 < 32; k0 += 4){
      float4 xr0 = *(const float4*)(xs + (rt*2+0)*36 + k0);
      float4 xr1 = *(const float4*)(xs + (rt*2+1)*36 + k0);
      float4 w0  = *(const float4*)(wc + (k0+0)*16 + jq*4);
      float4 w1  = *(const float4*)(wc + (k0+1)*16 + jq*4);
      float4 w2  = *(const float4*)(wc + (k0+2)*16 + jq*4);
      float4 w3  = *(const float4*)(wc + (k0+3)*16 + jq*4);
      acc0 = f4fma(acc0, xr0.x, w0); acc0 = f4fma(acc0, xr0.y, w1); acc0 = f4fma(acc0, xr0.z, w2); acc0 = f4fma(acc0, xr0.w, w3);
      acc1 = f4fma(acc1, xr1.x, w0); acc1 = f4fma(acc1, xr1.y, w1); acc1 = f4fma(acc1, xr1.z, w2); acc1 = f4fma(acc1, xr1.w, w3);
    }
    __syncthreads();
  }

  #pragma unroll
  for (int m = 0; m < 2; ++m){
    int gr = R0 + rt*2 + m;
    if (gr < N){
      float d = dis[gr];
      float4 a = (m==0) ? acc0 : acc1;
      PK2 pk;
      pk.h[0] = __float22half2_rn(make_float2(a.x*d, a.y*d));
      pk.h[1] = __float22half2_rn(make_float2(a.z*d, a.w*d));
      *(uint2*)(hs1h + (size_t)gr*16 + jq*4) = pk.u;
    }
  }
}

// ---- layer1 aggregate + bias/ReLU + xW2 -> hs2 fp16; 4 threads/node, chunked 2-phase ----
__global__ __launch_bounds__(256) void k_agg1(const __half* __restrict__ hs1h, const int* __restrict__ offs,
                                              const int* __restrict__ degi, const int* __restrict__ csr,
                                              const float* __restrict__ dis, const float* __restrict__ b1,
                                              const float* __restrict__ W2, __half* __restrict__ hs2h, int N){
  __shared__ float sW[112];
  __shared__ float sb[16];
  int t = threadIdx.x;
  if (t < 112) sW[t] = W2[t];
  if (t < 16)  sb[t] = b1[t];
  __syncthreads();

  int g = blockIdx.x*256 + t;
  int n = g >> 2;
  int q = g & 1;         // feature half
  int h = (g >> 1) & 1;  // edge parity
  if (n >= N) return;

  float a0[8] = {0,0,0,0,0,0,0,0};
  int st = offs[n], cnt = degi[n];

  for (int base = h; base < cnt; base += 16){
    int rr[8], ii[8];
    #pragma unroll
    for (int j = 0; j < 8; ++j){
      int i2 = base + 2*j;
      ii[j] = i2;
      int ic = (i2 < cnt) ? i2 : 0;
      rr[j] = csr[st + ic];
    }
    PK4 p[8];
    #pragma unroll
    for (int j = 0; j < 8; ++j)
      p[j].u = *(const uint4*)(hs1h + (size_t)rr[j]*16 + q*8);
    #pragma unroll
    for (int j = 0; j < 8; ++j){
      if (ii[j] < cnt){
        #pragma unroll
        for (int jj = 0; jj < 4; ++jj){
          float2 f = __half22float2(p[j].h[jj]);
          a0[2*jj]   += f.x;
          a0[2*jj+1] += f.y;
        }
      }
    }
  }
  // combine edge halves (lanes differing in bit 1)
  #pragma unroll
  for (int j = 0; j < 8; ++j) a0[j] += __shfl_xor(a0[j], 2);

  // self-loop term
  {
    PK4 ps; ps.u = *(const uint4*)(hs1h + (size_t)n*16 + q*8);
    #pragma unroll
    for (int jj = 0; jj < 4; ++jj){
      float2 fs = __half22float2(ps.h[jj]);
      a0[2*jj] += fs.x; a0[2*jj+1] += fs.y;
    }
  }

  float d = dis[n];
  float e[8];
  #pragma unroll
  for (int j = 0; j < 8; ++j)
    e[j] = fmaxf(fmaf(d, a0[j], sb[q*8 + j]), 0.f);

  float o[7] = {0,0,0,0,0,0,0};
  #pragma unroll
  for (int j = 0; j < 8; ++j){
    int f = q*8 + j;
    #pragma unroll
    for (int c = 0; c < 7; ++c) o[c] = fmaf(e[j], sW[f*7 + c], o[c]);
  }
  // combine feature halves (lanes differing in bit 0)
  #pragma unroll
  for (int c = 0; c < 7; ++c) o[c] += __shfl_xor(o[c], 1);

  if (q == 0 && h == 0){
    PK4 pk;
    pk.h[0] = __float22half2_rn(make_float2(o[0]*d, o[1]*d));
    pk.h[1] = __float22half2_rn(make_float2(o[2]*d, o[3]*d));
    pk.h[2] = __float22half2_rn(make_float2(o[4]*d, o[5]*d));
    pk.h[3] = __float22half2_rn(make_float2(o[6]*d, 0.f));
    *(uint4*)(hs2h + (size_t)n*8) = pk.u;
  }
}

// ---- layer2 aggregate + bias -> out fp32; 2 threads/node, chunked 2-phase ----
__global__ __launch_bounds__(256) void k_agg2(const __half* __restrict__ hs2h, const int* __restrict__ offs,
                                              const int* __restrict__ degi, const int* __restrict__ csr,
                                              const float* __restrict__ dis, const float* __restrict__ b2,
                                              float* __restrict__ out, int N){
  int g = blockIdx.x*256 + threadIdx.x;
  int n = g >> 1, h = g & 1;
  if (n >= N) return;

  float a0[7] = {0,0,0,0,0,0,0};
  int st = offs[n], cnt = degi[n];

  for (int base = h; base < cnt; base += 16){
    int rr[8], ii[8];
    #pragma unroll
    for (int j = 0; j < 8; ++j){
      int i2 = base + 2*j;
      ii[j] = i2;
      int ic = (i2 < cnt) ? i2 : 0;
      rr[j] = csr[st + ic];
    }
    PK4 p[8];
    #pragma unroll
    for (int j = 0; j < 8; ++j)
      p[j].u = *(const uint4*)(hs2h + (size_t)rr[j]*8);
    #pragma unroll
    for (int j = 0; j < 8; ++j){
      if (ii[j] < cnt){
        float2 f0 = __half22float2(p[j].h[0]);
        float2 f1 = __half22float2(p[j].h[1]);
        float2 f2 = __half22float2(p[j].h[2]);
        float2 f3 = __half22float2(p[j].h[3]);
        a0[0] += f0.x; a0[1] += f0.y;
        a0[2] += f1.x; a0[3] += f1.y;
        a0[4] += f2.x; a0[5] += f2.y;
        a0[6] += f3.x;
      }
    }
  }
  #pragma unroll
  for (int c = 0; c < 7; ++c) a0[c] += __shfl_xor(a0[c], 1);

  if (h == 0){
    float d = dis[n];
    PK4 ps; ps.u = *(const uint4*)(hs2h + (size_t)n*8);
    float s0 = __half22float2(ps.h[0]).x, s1 = __half22float2(ps.h[0]).y;
    float s2 = __half22float2(ps.h[1]).x, s3 = __half22float2(ps.h[1]).y;
    float s4 = __half22float2(ps.h[2]).x, s5 = __half22float2(ps.h[2]).y;
    float s6 = __half22float2(ps.h[3]).x;
    float* o = out + (size_t)n*7;
    o[0] = fmaf(d, a0[0] + s0, b2[0]);
    o[1] = fmaf(d, a0[1] + s1, b2[1]);
    o[2] = fmaf(d, a0[2] + s2, b2[2]);
    o[3] = fmaf(d, a0[3] + s3, b2[3]);
    o[4] = fmaf(d, a0[4] + s4, b2[4]);
    o[5] = fmaf(d, a0[5] + s5, b2[5]);
    o[6] = fmaf(d, a0[6] + s6, b2[6]);
  }
}

extern "C" void kernel_launch(void* const* d_in, const int* in_sizes, int n_in,
                              void* d_out, int out_size, void* d_ws, size_t ws_size,
                              hipStream_t stream){
  const float* x  = (const float*)d_in[0];
  const int*   ei = (const int*)d_in[1];
  const float* W1 = (const float*)d_in[2];
  const float* b1 = (const float*)d_in[3];
  const float* W2 = (const float*)d_in[4];
  const float* b2 = (const float*)d_in[5];
  float* out = (float*)d_out;

  const int N = in_sizes[0] / NF;      // 100000
  const int E = in_sizes[1] / 2;       // 3200000

  const int nbuck = (N + NPB - 1) / NPB;    // 782 (<= 2048)
  const int nblk  = (E + BLKE - 1) / BLKE;  // 782 (<= 1024 for E <= 4.19M)

  char* w = (char*)d_ws;
  size_t cur = 0;
  auto alloc = [&](size_t bytes)->char*{ char* p = w + cur; cur += (bytes + 255) & ~(size_t)255; return p; };
  int*    cnt2d  = (int*)   alloc((size_t)nblk*nbuck*4);
  int*    lpos2d = (int*)   alloc((size_t)nblk*nbuck*4);
  int*    soffT  = (int*)   alloc((size_t)nbuck*(nblk+1)*4);
  int*    sbaseT = (int*)   alloc((size_t)nbuck*nblk*4);
  int*    btot   = (int*)   alloc((size_t)(nbuck+1)*4);
  int*    degi   = (int*)   alloc((size_t)N*4);
  float*  dis    = (float*) alloc((size_t)N*4);
  int*    offs   = (int*)   alloc((size_t)N*4);
  int*    ebuf   = (int*)   alloc((size_t)nblk*BLKE*4);
  int*    csr    = (int*)   alloc((size_t)E*4);
  __half* hs1h   = (__half*)alloc((size_t)N*16*2);
  __half* hs2h   = (__half*)alloc((size_t)N*8*2);
  (void)ws_size; (void)n_in; (void)out_size;

  int gM  = (N + 127) / 128;
  int g2N = (2*N + 255) / 256;
  int g4N = (4*N + 255) / 256;

  k_blocal<<<nblk, 256, 0, stream>>>(ei, E, nbuck, ebuf, cnt2d, lpos2d);
  k_meta  <<<nbuck, 256, 0, stream>>>(cnt2d, lpos2d, nblk, nbuck, soffT, sbaseT, btot);
  k_bsort <<<nbuck, 256, 0, stream>>>(ebuf, soffT, sbaseT, btot, degi, dis, offs, csr, N, nblk);
  k_gemm1 <<<gM, 256, 0, stream>>>(x, W1, dis, hs1h, N);
  k_agg1  <<<g4N, 256, 0, stream>>>(hs1h, offs, degi, csr, dis, b1, W2, hs2h, N);
  k_agg2  <<<g2N, 256, 0, stream>>>(hs2h, offs, degi, csr, dis, b2, out, N);
}

// Round 11
// 155.871 us; speedup vs baseline: 1.1702x; 1.0643x over previous
//
#include <hip/hip_runtime.h>
#include <hip/hip_fp16.h>

#define NF    512
#define BLKE  4096
#define SHIFT 7
#define NPB   128      // nodes per bucket

#define AS1 __attribute__((address_space(1)))
#define AS3 __attribute__((address_space(3)))

__device__ inline float4 f4fma(float4 a, float s, float4 b){
  return make_float4(fmaf(s,b.x,a.x), fmaf(s,b.y,a.y), fmaf(s,b.z,a.z), fmaf(s,b.w,a.w));
}

union PK4 { uint4 u; __half2 h[4]; };
union PK2 { uint2 u; __half2 h[2]; };

// ---- Pass A: per-block bucket grouping (4096 edges/block); packed (cnt<<16)|lpos metadata ----
__global__ __launch_bounds__(256) void k_blocal(const int* __restrict__ ei, int E, int nbuck,
                                                int* __restrict__ ebuf, unsigned* __restrict__ cpos){
  __shared__ int lh[2048];
  __shared__ int part[256];
  __shared__ int lbuf[BLKE];
  __shared__ int s_is64;
  int t = threadIdx.x;
  int blk = blockIdx.x;
  int e0 = blk * BLKE;
  int cnt = min(BLKE, E - e0);

  if (t == 0) s_is64 = 1;
  __syncthreads();
  int found = 0;
  for (int k = t; k < min(cnt, 2048); k += 256) found |= (ei[2*(e0+k)+1] != 0);
  if (found) s_is64 = 0;
  __syncthreads();
  int is64 = s_is64;

  int rr[16], cc[16];
  #pragma unroll
  for (int j = 0; j < 16; ++j){
    int k = j*256 + t;
    int idx = e0 + k;
    if (k < cnt){
      if (is64){ rr[j] = ei[2*idx]; cc[j] = ei[2*(E+idx)]; }
      else     { rr[j] = ei[idx];   cc[j] = ei[E+idx];     }
    } else { rr[j] = -1; cc[j] = 0; }
  }

  for (int i = t; i < nbuck; i += 256) lh[i] = 0;
  __syncthreads();
  #pragma unroll
  for (int j = 0; j < 16; ++j)
    if (rr[j] >= 0) atomicAdd(&lh[cc[j] >> SHIFT], 1);
  __syncthreads();

  int per = (nbuck + 255) >> 8;   // <= 8
  int myv[8];
  int s = 0;
  #pragma unroll
  for (int j = 0; j < 8; ++j){
    int i = t*per + j;
    int v = (j < per && i < nbuck) ? lh[i] : 0;
    myv[j] = v; s += v;
  }
  part[t] = s; __syncthreads();
  for (int off = 1; off < 256; off <<= 1){
    int a = part[t];
    int u = (t >= off) ? part[t-off] : 0;
    __syncthreads();
    part[t] = a + u;
    __syncthreads();
  }
  int run = part[t] - s;
  #pragma unroll
  for (int j = 0; j < 8; ++j){
    int i = t*per + j;
    if (j < per && i < nbuck){
      cpos[(size_t)blk*nbuck + i] = ((unsigned)myv[j] << 16) | (unsigned)run;
      lh[i] = run;
      run += myv[j];
    }
  }
  __syncthreads();

  #pragma unroll
  for (int j = 0; j < 16; ++j){
    if (rr[j] >= 0){
      int b = cc[j] >> SHIFT;
      int p = atomicAdd(&lh[b], 1);
      lbuf[p] = (rr[j] << SHIFT) | (cc[j] & (NPB-1));
    }
  }
  __syncthreads();
  for (int k = t; k < cnt; k += 256) ebuf[e0 + k] = lbuf[k];   // coalesced flush
}

// ---- Pass B: transpose packed metadata to bucket-major + per-bucket totals ----
__global__ __launch_bounds__(256) void k_meta(const unsigned* __restrict__ cpos,
                                              int nblk, int nbuck,
                                              unsigned* __restrict__ cposT, int* __restrict__ btot){
  __shared__ int part[256];
  int b = blockIdx.x, t = threadIdx.x;

  int per = (nblk + 255) >> 8;   // <= 4 (nblk <= 1024)
  int s = 0;
  #pragma unroll
  for (int j = 0; j < 4; ++j){
    int i = t*per + j;
    if (j < per && i < nblk){
      unsigned u = cpos[(size_t)i*nbuck + b];   // strided column read
      cposT[(size_t)b*nblk + i] = u;            // coalesced write
      s += (int)(u >> 16);
    }
  }
  part[t] = s; __syncthreads();
  for (int off = 128; off > 0; off >>= 1){
    if (t < off) part[t] += part[t + off];
    __syncthreads();
  }
  if (t == 0) btot[b] = part[0];
}

// ---- Pass C: per-bucket scan(metadata)+stage+count+scatter; emits degi/dis/offs/csr ----
__global__ __launch_bounds__(256) void k_bsort(const int* __restrict__ ebuf, const unsigned* __restrict__ cposT,
                                               const int* __restrict__ btot,
                                               int* __restrict__ degi, float* __restrict__ dis,
                                               int* __restrict__ offs, int* __restrict__ csr,
                                               int N, int nblk){
  __shared__ int soff[1025];
  __shared__ int sbase[1024];
  __shared__ int part[256];
  __shared__ int lcnt[NPB];
  __shared__ int sd[NPB];
  __shared__ int lbuf[6144];   // mean bucket = 4092; fallback path covers overflow
  int b = blockIdx.x, t = threadIdx.x;
  int n0 = b * NPB;
  int nn = min(NPB, N - n0);

  // ebase[b] = sum btot[0..b)
  int accE = 0;
  for (int i = t; i < b; i += 256) accE += btot[i];
  part[t] = accE; __syncthreads();
  for (int off = 128; off > 0; off >>= 1){
    if (t < off) part[t] += part[t + off];
    __syncthreads();
  }
  int eb = part[0];
  __syncthreads();

  // build soff (exclusive scan of per-block counts) + sbase from packed metadata
  int per = (nblk + 255) >> 8;   // <= 4
  int myv[4];
  int s = 0;
  #pragma unroll
  for (int j = 0; j < 4; ++j){
    int i = t*per + j;
    int v = 0;
    if (j < per && i < nblk){
      unsigned u = cposT[(size_t)b*nblk + i];   // coalesced
      v = (int)(u >> 16);
      sbase[i] = i*BLKE + (int)(u & 0xFFFFu);
    }
    myv[j] = v; s += v;
  }
  part[t] = s; __syncthreads();
  for (int off = 1; off < 256; off <<= 1){
    int a = part[t];
    int u = (t >= off) ? part[t-off] : 0;
    __syncthreads();
    part[t] = a + u;
    __syncthreads();
  }
  int run = part[t] - s;
  #pragma unroll
  for (int j = 0; j < 4; ++j){
    int i = t*per + j;
    if (j < per && i < nblk){
      soff[i] = run;
      run += myv[j];
    }
  }
  if (t == 255) soff[nblk] = part[255];
  if (t < NPB) lcnt[t] = 0;
  __syncthreads();

  int size = soff[nblk];
  bool staged = (size <= 6144);

  // pass 1: merge-path march — stage into LDS + count per node
  int PER = (size + 255) >> 8;
  int k = t * PER, kend = min(k + PER, size);
  if (k < kend){
    int lo = 0, hi = nblk - 1;
    while (lo < hi){ int mid = (lo + hi + 1) >> 1; if (soff[mid] <= k) lo = mid; else hi = mid - 1; }
    int seg = lo;
    while (k < kend){
      int se = soff[seg+1];
      const int* src = ebuf + sbase[seg] - soff[seg];
      int e1 = min(kend, se);
      for (; k < e1; ++k){
        int v = src[k];
        if (staged) lbuf[k] = v;
        atomicAdd(&lcnt[v & (NPB-1)], 1);
      }
      ++seg;
    }
  }
  __syncthreads();

  // emit degi/dis; scan counts -> cursors + offs
  int own = 0;
  if (t < nn){
    own = lcnt[t];
    degi[n0 + t] = own;
    dis[n0 + t]  = rsqrtf((float)(own + 1));   // +1 self-loop
    sd[t] = own;
  }
  __syncthreads();
  for (int off = 1; off < NPB; off <<= 1){
    int v = (t < nn && t >= off) ? sd[t-off] : 0;
    __syncthreads();
    if (t < nn) sd[t] += v;
    __syncthreads();
  }
  if (t < nn){
    int pref = sd[t] - own;
    lcnt[t] = pref;
    offs[n0 + t] = eb + pref;
  }
  __syncthreads();

  // pass 2: scatter
  if (staged){
    for (int k2 = t; k2 < size; k2 += 256){
      int v = lbuf[k2];
      int p = atomicAdd(&lcnt[v & (NPB-1)], 1);
      csr[eb + p] = v >> SHIFT;
    }
  } else {
    int k3 = t * PER, kend3 = min(k3 + PER, size);
    if (k3 < kend3){
      int lo = 0, hi = nblk - 1;
      while (lo < hi){ int mid = (lo + hi + 1) >> 1; if (soff[mid] <= k3) lo = mid; else hi = mid - 1; }
      int seg = lo;
      while (k3 < kend3){
        int se = soff[seg+1];
        const int* src = ebuf + sbase[seg] - soff[seg];
        int e1 = min(kend3, se);
        for (; k3 < e1; ++k3){
          int v = src[k3];
          int p = atomicAdd(&lcnt[v & (NPB-1)], 1);
          csr[eb + p] = v >> SHIFT;
        }
        ++seg;
      }
    }
  }
}

// ---- hs1 = fp16( dis * (x @ W1) ); BM=128, BK=32, global_load_lds + XOR-swizzled LDS ----
// swz(r) = (r&7)^((r>>3)&7); LDS xs is LINEAR [128][32]; row r col-group g holds src group g^swz(r).
__global__ __launch_bounds__(256) void k_gemm1(const float* __restrict__ x, const float* __restrict__ W1,
                                               const float* __restrict__ dis, __half* __restrict__ hs1h, int N){
  __shared__ float xs[128*32];
  __shared__ float wc[512];
  int t  = threadIdx.x;
  int R0 = blockIdx.x*128;
  int lr = t >> 3;                  // 0..31 (= wave*8 + (lane>>3))
  int lane7 = t & 7;
  int w  = t >> 6;                  // wave id (uniform per wave)
  int rt = t >> 2;
  int jq = t & 3;

  int grc[4], cgs[4];
  #pragma unroll
  for (int li = 0; li < 4; ++li){
    int row = lr + li*32;
    int gr  = R0 + row;
    grc[li] = (gr < N) ? gr : 0;
    int swz = (row & 7) ^ ((row >> 3) & 7);
    cgs[li] = (lane7 ^ swz) << 2;   // source col offset (floats) within 32-col chunk
  }

  int r0 = rt*2, r1 = r0 + 1;
  int sz0 = ((r0 & 7) ^ ((r0 >> 3) & 7));
  int sz1 = ((r1 & 7) ^ ((r1 >> 3) & 7));

  float4 acc0 = make_float4(0,0,0,0), acc1 = acc0;

  for (int kc = 0; kc < NF; kc += 32){
    #pragma unroll
    for (int li = 0; li < 4; ++li){
      const float* src = x + (size_t)grc[li]*NF + kc + cgs[li];
      float* ldst = xs + ((li*32 + w*8) << 5);   // wave-uniform base; lane writes base+lane*16B
      __builtin_amdgcn_global_load_lds((const AS1 void*)src, (AS3 void*)ldst, 16, 0, 0);
    }
    wc[t]       = W1[kc*16 + t];
    wc[t + 256] = W1[kc*16 + t + 256];
    __syncthreads();

    #pragma unroll
    for (int k0 = 0; k0 < 32; k0 += 4){
      int kg = k0 >> 2;
      float4 xr0 = *(const float4*)(xs + (r0 << 5) + ((kg ^ sz0) << 2));
      float4 xr1 = *(const float4*)(xs + (r1 << 5) + ((kg ^ sz1) << 2));
      float4 w0  = *(const float4*)(wc + (k0+0)*16 + jq*4);
      float4 w1  = *(const float4*)(wc + (k0+1)*16 + jq*4);
      float4 w2  = *(const float4*)(wc + (k0+2)*16 + jq*4);
      float4 w3  = *(const float4*)(wc + (k0+3)*16 + jq*4);
      acc0 = f4fma(acc0, xr0.x, w0); acc0 = f4fma(acc0, xr0.y, w1); acc0 = f4fma(acc0, xr0.z, w2); acc0 = f4fma(acc0, xr0.w, w3);
      acc1 = f4fma(acc1, xr1.x, w0); acc1 = f4fma(acc1, xr1.y, w1); acc1 = f4fma(acc1, xr1.z, w2); acc1 = f4fma(acc1, xr1.w, w3);
    }
    __syncthreads();
  }

  #pragma unroll
  for (int m = 0; m < 2; ++m){
    int gr = R0 + rt*2 + m;
    if (gr < N){
      float d = dis[gr];
      float4 a = (m==0) ? acc0 : acc1;
      PK2 pk;
      pk.h[0] = __float22half2_rn(make_float2(a.x*d, a.y*d));
      pk.h[1] = __float22half2_rn(make_float2(a.z*d, a.w*d));
      *(uint2*)(hs1h + (size_t)gr*16 + jq*4) = pk.u;
    }
  }
}

// ---- layer1 aggregate + bias/ReLU + xW2 -> hs2 fp16; 4 threads/node, chunked 2-phase ----
__global__ __launch_bounds__(256) void k_agg1(const __half* __restrict__ hs1h, const int* __restrict__ offs,
                                              const int* __restrict__ degi, const int* __restrict__ csr,
                                              const float* __restrict__ dis, const float* __restrict__ b1,
                                              const float* __restrict__ W2, __half* __restrict__ hs2h, int N){
  __shared__ float sW[112];
  __shared__ float sb[16];
  int t = threadIdx.x;
  if (t < 112) sW[t] = W2[t];
  if (t < 16)  sb[t] = b1[t];
  __syncthreads();

  int g = blockIdx.x*256 + t;
  int n = g >> 2;
  int q = g & 1;         // feature half
  int h = (g >> 1) & 1;  // edge parity
  if (n >= N) return;

  float a0[8] = {0,0,0,0,0,0,0,0};
  int st = offs[n], cnt = degi[n];

  for (int base = h; base < cnt; base += 16){
    int rr[8], ii[8];
    #pragma unroll
    for (int j = 0; j < 8; ++j){
      int i2 = base + 2*j;
      ii[j] = i2;
      int ic = (i2 < cnt) ? i2 : 0;
      rr[j] = csr[st + ic];
    }
    PK4 p[8];
    #pragma unroll
    for (int j = 0; j < 8; ++j)
      p[j].u = *(const uint4*)(hs1h + (size_t)rr[j]*16 + q*8);
    #pragma unroll
    for (int j = 0; j < 8; ++j){
      if (ii[j] < cnt){
        #pragma unroll
        for (int jj = 0; jj < 4; ++jj){
          float2 f = __half22float2(p[j].h[jj]);
          a0[2*jj]   += f.x;
          a0[2*jj+1] += f.y;
        }
      }
    }
  }
  // combine edge halves (lanes differing in bit 1)
  #pragma unroll
  for (int j = 0; j < 8; ++j) a0[j] += __shfl_xor(a0[j], 2);

  // self-loop term
  {
    PK4 ps; ps.u = *(const uint4*)(hs1h + (size_t)n*16 + q*8);
    #pragma unroll
    for (int jj = 0; jj < 4; ++jj){
      float2 fs = __half22float2(ps.h[jj]);
      a0[2*jj] += fs.x; a0[2*jj+1] += fs.y;
    }
  }

  float d = dis[n];
  float e[8];
  #pragma unroll
  for (int j = 0; j < 8; ++j)
    e[j] = fmaxf(fmaf(d, a0[j], sb[q*8 + j]), 0.f);

  float o[7] = {0,0,0,0,0,0,0};
  #pragma unroll
  for (int j = 0; j < 8; ++j){
    int f = q*8 + j;
    #pragma unroll
    for (int c = 0; c < 7; ++c) o[c] = fmaf(e[j], sW[f*7 + c], o[c]);
  }
  // combine feature halves (lanes differing in bit 0)
  #pragma unroll
  for (int c = 0; c < 7; ++c) o[c] += __shfl_xor(o[c], 1);

  if (q == 0 && h == 0){
    PK4 pk;
    pk.h[0] = __float22half2_rn(make_float2(o[0]*d, o[1]*d));
    pk.h[1] = __float22half2_rn(make_float2(o[2]*d, o[3]*d));
    pk.h[2] = __float22half2_rn(make_float2(o[4]*d, o[5]*d));
    pk.h[3] = __float22half2_rn(make_float2(o[6]*d, 0.f));
    *(uint4*)(hs2h + (size_t)n*8) = pk.u;
  }
}

// ---- layer2 aggregate + bias -> out fp32; 2 threads/node, chunked 2-phase ----
__global__ __launch_bounds__(256) void k_agg2(const __half* __restrict__ hs2h, const int* __restrict__ offs,
                                              const int* __restrict__ degi, const int* __restrict__ csr,
                                              const float* __restrict__ dis, const float* __restrict__ b2,
                                              float* __restrict__ out, int N){
  int g = blockIdx.x*256 + threadIdx.x;
  int n = g >> 1, h = g & 1;
  if (n >= N) return;

  float a0[7] = {0,0,0,0,0,0,0};
  int st = offs[n], cnt = degi[n];

  for (int base = h; base < cnt; base += 16){
    int rr[8], ii[8];
    #pragma unroll
    for (int j = 0; j < 8; ++j){
      int i2 = base + 2*j;
      ii[j] = i2;
      int ic = (i2 < cnt) ? i2 : 0;
      rr[j] = csr[st + ic];
    }
    PK4 p[8];
    #pragma unroll
    for (int j = 0; j < 8; ++j)
      p[j].u = *(const uint4*)(hs2h + (size_t)rr[j]*8);
    #pragma unroll
    for (int j = 0; j < 8; ++j){
      if (ii[j] < cnt){
        float2 f0 = __half22float2(p[j].h[0]);
        float2 f1 = __half22float2(p[j].h[1]);
        float2 f2 = __half22float2(p[j].h[2]);
        float2 f3 = __half22float2(p[j].h[3]);
        a0[0] += f0.x; a0[1] += f0.y;
        a0[2] += f1.x; a0[3] += f1.y;
        a0[4] += f2.x; a0[5] += f2.y;
        a0[6] += f3.x;
      }
    }
  }
  #pragma unroll
  for (int c = 0; c < 7; ++c) a0[c] += __shfl_xor(a0[c], 1);

  if (h == 0){
    float d = dis[n];
    PK4 ps; ps.u = *(const uint4*)(hs2h + (size_t)n*8);
    float s0 = __half22float2(ps.h[0]).x, s1 = __half22float2(ps.h[0]).y;
    float s2 = __half22float2(ps.h[1]).x, s3 = __half22float2(ps.h[1]).y;
    float s4 = __half22float2(ps.h[2]).x, s5 = __half22float2(ps.h[2]).y;
    float s6 = __half22float2(ps.h[3]).x;
    float* o = out + (size_t)n*7;
    o[0] = fmaf(d, a0[0] + s0, b2[0]);
    o[1] = fmaf(d, a0[1] + s1, b2[1]);
    o[2] = fmaf(d, a0[2] + s2, b2[2]);
    o[3] = fmaf(d, a0[3] + s3, b2[3]);
    o[4] = fmaf(d, a0[4] + s4, b2[4]);
    o[5] = fmaf(d, a0[5] + s5, b2[5]);
    o[6] = fmaf(d, a0[6] + s6, b2[6]);
  }
}

extern "C" void kernel_launch(void* const* d_in, const int* in_sizes, int n_in,
                              void* d_out, int out_size, void* d_ws, size_t ws_size,
                              hipStream_t stream){
  const float* x  = (const float*)d_in[0];
  const int*   ei = (const int*)d_in[1];
  const float* W1 = (const float*)d_in[2];
  const float* b1 = (const float*)d_in[3];
  const float* W2 = (const float*)d_in[4];
  const float* b2 = (const float*)d_in[5];
  float* out = (float*)d_out;

  const int N = in_sizes[0] / NF;      // 100000
  const int E = in_sizes[1] / 2;       // 3200000

  const int nbuck = (N + NPB - 1) / NPB;    // 782 (<= 2048)
  const int nblk  = (E + BLKE - 1) / BLKE;  // 782 (<= 1024 for E <= 4.19M)

  char* w = (char*)d_ws;
  size_t cur = 0;
  auto alloc = [&](size_t bytes)->char*{ char* p = w + cur; cur += (bytes + 255) & ~(size_t)255; return p; };
  unsigned* cpos  = (unsigned*)alloc((size_t)nblk*nbuck*4);
  unsigned* cposT = (unsigned*)alloc((size_t)nbuck*nblk*4);
  int*    btot   = (int*)   alloc((size_t)(nbuck+1)*4);
  int*    degi   = (int*)   alloc((size_t)N*4);
  float*  dis    = (float*) alloc((size_t)N*4);
  int*    offs   = (int*)   alloc((size_t)N*4);
  int*    ebuf   = (int*)   alloc((size_t)nblk*BLKE*4);
  int*    csr    = (int*)   alloc((size_t)E*4);
  __half* hs1h   = (__half*)alloc((size_t)N*16*2);
  __half* hs2h   = (__half*)alloc((size_t)N*8*2);
  (void)ws_size; (void)n_in; (void)out_size;

  int gM  = (N + 127) / 128;
  int g2N = (2*N + 255) / 256;
  int g4N = (4*N + 255) / 256;

  k_blocal<<<nblk, 256, 0, stream>>>(ei, E, nbuck, ebuf, cpos);
  k_meta  <<<nbuck, 256, 0, stream>>>(cpos, nblk, nbuck, cposT, btot);
  k_bsort <<<nbuck, 256, 0, stream>>>(ebuf, cposT, btot, degi, dis, offs, csr, N, nblk);
  k_gemm1 <<<gM, 256, 0, stream>>>(x, W1, dis, hs1h, N);
  k_agg1  <<<g4N, 256, 0, stream>>>(hs1h, offs, degi, csr, dis, b1, W2, hs2h, N);
  k_agg2  <<<g2N, 256, 0, stream>>>(hs2h, offs, degi, csr, dis, b2, out, N);
}